// Round 8
// baseline (338.117 us; speedup 1.0000x reference)
//
#include <hip/hip_runtime.h>
#include <hip/hip_bf16.h>
#include <cstdint>

typedef __bf16 bf16;
typedef __bf16 bf16_8 __attribute__((ext_vector_type(8)));
typedef __bf16 bf16_4 __attribute__((ext_vector_type(4)));
typedef float f32_4 __attribute__((ext_vector_type(4)));
typedef short s16x4 __attribute__((ext_vector_type(4)));
typedef short s16x8 __attribute__((ext_vector_type(8)));

#define MFMA_16x16x32(a, b, c) __builtin_amdgcn_mfma_f32_16x16x32_bf16((a), (b), (c), 0, 0, 0)

__device__ __forceinline__ void gll16(const void* g, void* l) {
  __builtin_amdgcn_global_load_lds((const __attribute__((address_space(1))) void*)g,
                                   (__attribute__((address_space(3))) void*)l, 16, 0, 0);
}

__device__ __forceinline__ float exp2fast(float x) {
#if __has_builtin(__builtin_amdgcn_exp2f)
  return __builtin_amdgcn_exp2f(x);
#else
  return __exp2f(x);
#endif
}

__device__ __forceinline__ unsigned bfbits(float x) {
  bf16 b = (bf16)x;
  return (unsigned)__builtin_bit_cast(unsigned short, b);
}

// ---------------- fused fp32 -> bf16 converter (activations + weights) -------
// y in [0,3): q/k/v activations, 8 elems/thread (4096 x-blocks).
// y == 3   : all four weight matrices concatenated, 4 elems/thread.
//            Wq (widx 0) is PRE-SCALED by (1/sqrt(64))*log2(e) so attention
//            scores arrive in exp2-space: softmax is a bare v_exp per score
//            (bf16 rounding is scale-invariant; fixed bias cancels in P/sum).
__global__ __launch_bounds__(256) void cvt_all(const float* __restrict__ q,
                                               const float* __restrict__ k,
                                               const float* __restrict__ v,
                                               const float* __restrict__ w0,
                                               const float* __restrict__ w1,
                                               const float* __restrict__ w2,
                                               const float* __restrict__ w3,
                                               bf16* __restrict__ qb,
                                               bf16* __restrict__ kb,
                                               bf16* __restrict__ vb,
                                               bf16* __restrict__ wb) {
  const int y = blockIdx.y;
  if (y < 3) {
    const float* src = y == 0 ? q : (y == 1 ? k : v);
    bf16* dst = y == 0 ? qb : (y == 1 ? kb : vb);
    size_t i = ((size_t)blockIdx.x * 256 + threadIdx.x) * 8;
    float4 f0 = *(const float4*)(src + i);
    float4 f1 = *(const float4*)(src + i + 4);
    bf16_8 o;
    o[0] = (bf16)f0.x; o[1] = (bf16)f0.y; o[2] = (bf16)f0.z; o[3] = (bf16)f0.w;
    o[4] = (bf16)f1.x; o[5] = (bf16)f1.y; o[6] = (bf16)f1.z; o[7] = (bf16)f1.w;
    *(bf16_8*)(dst + i) = o;
  } else {
    size_t i = ((size_t)blockIdx.x * 256 + threadIdx.x) * 4;
    const int widx = (int)(i >> 20);                 // block-uniform
    const size_t off = i & (((size_t)1 << 20) - 1);
    const float* srcs[4] = {w0, w1, w2, w3};
    const float sc = (widx == 0) ? 0.18033688f : 1.0f;  // 0.125*log2(e)
    float4 f = *(const float4*)(srcs[widx] + off);
    bf16_4 o;
    o[0] = (bf16)(f.x * sc); o[1] = (bf16)(f.y * sc);
    o[2] = (bf16)(f.z * sc); o[3] = (bf16)(f.w * sc);
    *(bf16_4*)(wb + i) = o;
  }
}

// ---------------- fused QKV projection GEMM ----------------------------------
// bf16 A via global_load_lds; T2 source-side slot swizzle (row&3) inverted at
// fragment read (neutral but harmless on this 2-phase structure).
// blockIdx.y in [0,24): tensor = y>>3 (0:q,1:k,2:v), n0 = (y&7)*128.
// NEW: for Q/K the MFMA operands are SWAPPED (A=W-frag, B=act-frag, uniform
// branch) so the C-layout is col=l15=token, row=quad*4+i=n -> each lane packs
// 4 consecutive n as one bf16_4 8B store (16 stores vs 64 scalar 2B stores).
// V unchanged: written TRANSPOSED into Vt[(b*16+h)*64+d][s] with keys
// PAIR-PERMUTED within each 64-block:
//   k = t*16 + q*4 + j  ->  (t>>1)*32 + q*8 + (t&1)*4 + j
// so attn's PV step fetches x32 A-frags as single b128 LDS reads.
__global__ __launch_bounds__(256) void gemm_qkv(const bf16* __restrict__ Aq,
                                                const bf16* __restrict__ Ak,
                                                const bf16* __restrict__ Av,
                                                const bf16* __restrict__ W,
                                                bf16* __restrict__ Qp,
                                                bf16* __restrict__ Kp,
                                                bf16* __restrict__ Vt) {
  constexpr int BM = 128, BK = 32, K = 1024, N = 1024, M_S = 2048;
  __shared__ alignas(16) bf16 As[2][BM * BK];
  __shared__ alignas(16) bf16 Bs[2][BM * BK];

  const int tid = threadIdx.x;
  const int wave = tid >> 6, lane = tid & 63;
  const int quad = lane >> 4, l15 = lane & 15;
  const int wm = (wave & 1) * 64, wn = (wave >> 1) * 64;
  const int tensor = blockIdx.y >> 3;
  const int n0 = (blockIdx.y & 7) * 128;
  const size_t m0 = (size_t)blockIdx.x * BM;

  const bf16* A = tensor == 0 ? Aq : (tensor == 1 ? Ak : Av);
  const bf16* Bt = W + ((size_t)tensor << 20);

  f32_4 acc[4][4] = {};

  // swizzled source: lane covers row lane>>2, 16B slot (lane&3)^((lane>>2)&3)
  const size_t g_laneoff = (size_t)(lane >> 2) * K +
                           (size_t)(((lane & 3) ^ ((lane >> 2) & 3)) * 8);
  const bf16* Ag = A + (m0 + wave * 32) * (size_t)K + g_laneoff;
  const bf16* Bg = Bt + ((size_t)n0 + wave * 32) * (size_t)K + g_laneoff;
  const int l_off = wave * 32 * BK + lane * 8;

  auto stage = [&](int b, int k0) {
    gll16(Ag + k0, &As[b][l_off]);
    gll16(Ag + 16 * (size_t)K + k0, &As[b][l_off + 16 * BK]);
    gll16(Bg + k0, &Bs[b][l_off]);
    gll16(Bg + 16 * (size_t)K + k0, &Bs[b][l_off + 16 * BK]);
  };

  stage(0, 0);
  int buf = 0;
  for (int k0 = 0; k0 < K; k0 += BK, buf ^= 1) {
    __syncthreads();
    if (k0 + BK < K) stage(buf ^ 1, k0 + BK);

    const int slot = (quad ^ (l15 & 3)) * 8;   // inverse swizzle at read
    bf16_8 af[4], bfr[4];
#pragma unroll
    for (int mt = 0; mt < 4; ++mt)
      af[mt] = *(const bf16_8*)&As[buf][(wm + mt * 16 + l15) * BK + slot];
#pragma unroll
    for (int nt = 0; nt < 4; ++nt)
      bfr[nt] = *(const bf16_8*)&Bs[buf][(wn + nt * 16 + l15) * BK + slot];
    if (tensor < 2) {
      // swapped: D'[n][token] -> coalescible epilogue
#pragma unroll
      for (int mt = 0; mt < 4; ++mt)
#pragma unroll
        for (int nt = 0; nt < 4; ++nt)
          acc[mt][nt] = MFMA_16x16x32(bfr[nt], af[mt], acc[mt][nt]);
    } else {
#pragma unroll
      for (int mt = 0; mt < 4; ++mt)
#pragma unroll
        for (int nt = 0; nt < 4; ++nt)
          acc[mt][nt] = MFMA_16x16x32(af[mt], bfr[nt], acc[mt][nt]);
    }
  }

  if (tensor < 2) {
    // swapped C-layout: col=l15=token, row=quad*4+i = n within nt-tile
    bf16* C = tensor == 0 ? Qp : Kp;
#pragma unroll
    for (int mt = 0; mt < 4; ++mt) {
      const size_t token = m0 + wm + mt * 16 + l15;
      bf16* cr = C + token * N + n0 + wn + quad * 4;
#pragma unroll
      for (int nt = 0; nt < 4; ++nt) {
        bf16_4 pk;
        pk[0] = (bf16)acc[mt][nt][0]; pk[1] = (bf16)acc[mt][nt][1];
        pk[2] = (bf16)acc[mt][nt][2]; pk[3] = (bf16)acc[mt][nt][3];
        *(bf16_4*)(cr + nt * 16) = pk;
      }
    }
  } else {
    const int bb = (int)(m0 >> 11);
    const int sbase = (int)(m0 & 2047) + wm;
#pragma unroll
    for (int mt = 0; mt < 4; ++mt)
#pragma unroll
      for (int nt = 0; nt < 4; ++nt) {
        int col = n0 + wn + nt * 16 + l15;
        bf16_4 pk;
        pk[0] = (bf16)acc[mt][nt][0]; pk[1] = (bf16)acc[mt][nt][1];
        pk[2] = (bf16)acc[mt][nt][2]; pk[3] = (bf16)acc[mt][nt][3];
        // pair-permuted key index: mt*16+quad*4 -> (mt>>1)*32 + quad*8 + (mt&1)*4
        bf16* dst = Vt + ((size_t)(bb * 16 + (col >> 6)) * 64 + (col & 63)) * M_S +
                    sbase + (mt >> 1) * 32 + quad * 8 + (mt & 1) * 4;
        *(bf16_4*)dst = pk;
      }
  }
}

// ---------------- output projection GEMM (fp32 out) --------------------------
// Swapped operands throughout: lane holds 4 consecutive n as fp32 ->
// 16 dwordx4 stores replace 64 dword stores on the 32 MB C-write.
__global__ __launch_bounds__(256) void gemm_out(const bf16* __restrict__ A,
                                                const bf16* __restrict__ Bt,
                                                float* __restrict__ C,
                                                int M, int N, int K) {
  constexpr int BM = 128, BN = 128, BK = 32;
  __shared__ alignas(16) bf16 As[2][BM * BK];
  __shared__ alignas(16) bf16 Bs[2][BN * BK];

  const int tid = threadIdx.x;
  const int wave = tid >> 6, lane = tid & 63;
  const int quad = lane >> 4, l15 = lane & 15;
  const int wm = (wave & 1) * 64, wn = (wave >> 1) * 64;
  const size_t m0 = (size_t)blockIdx.x * BM;
  const size_t n0 = (size_t)blockIdx.y * BN;

  f32_4 acc[4][4] = {};

  const size_t g_laneoff = (size_t)(lane >> 2) * K +
                           (size_t)(((lane & 3) ^ ((lane >> 2) & 3)) * 8);
  const bf16* Ag = A + (m0 + wave * 32) * (size_t)K + g_laneoff;
  const bf16* Bg = Bt + (n0 + wave * 32) * (size_t)K + g_laneoff;
  const int l_off = wave * 32 * BK + lane * 8;

  auto stage = [&](int b, int k0) {
    gll16(Ag + k0, &As[b][l_off]);
    gll16(Ag + 16 * (size_t)K + k0, &As[b][l_off + 16 * BK]);
    gll16(Bg + k0, &Bs[b][l_off]);
    gll16(Bg + 16 * (size_t)K + k0, &Bs[b][l_off + 16 * BK]);
  };

  stage(0, 0);
  int buf = 0;
  for (int k0 = 0; k0 < K; k0 += BK, buf ^= 1) {
    __syncthreads();
    if (k0 + BK < K) stage(buf ^ 1, k0 + BK);

    const int slot = (quad ^ (l15 & 3)) * 8;
    bf16_8 af[4], bfr[4];
#pragma unroll
    for (int mt = 0; mt < 4; ++mt)
      af[mt] = *(const bf16_8*)&As[buf][(wm + mt * 16 + l15) * BK + slot];
#pragma unroll
    for (int nt = 0; nt < 4; ++nt)
      bfr[nt] = *(const bf16_8*)&Bs[buf][(wn + nt * 16 + l15) * BK + slot];
#pragma unroll
    for (int mt = 0; mt < 4; ++mt)
#pragma unroll
      for (int nt = 0; nt < 4; ++nt)
        acc[mt][nt] = MFMA_16x16x32(bfr[nt], af[mt], acc[mt][nt]);  // swapped
  }

  // swapped C-layout: col=l15=token, row=quad*4+i = n within nt-tile
#pragma unroll
  for (int mt = 0; mt < 4; ++mt) {
    const size_t token = m0 + wm + mt * 16 + l15;
    float* cr = C + token * N + n0 + wn + quad * 4;
#pragma unroll
    for (int nt = 0; nt < 4; ++nt)
      *(f32_4*)(cr + nt * 16) = acc[mt][nt];
  }
}

// ---------------- fused flash attention, register-resident P -----------------
// 4 waves x 32 q-rows (best measured structure). K-tiles of 64, KV dbuf.
// S^T = K.Q^T (Q pre-scaled to exp2-space) -> softmax is a bare v_exp;
// exp(S^T) C-layout IS half a x32 B-frag; pair-permuted Vt makes each b128
// V read the matching x32 A-frag. Denominator via ones-MFMA.
// XCD-grouping swizzle keeps one head's K+V resident in one XCD's L2.
// Per-wave ballot anym; s_setprio(1) around MFMA clusters.
// NEW: uniform branch on anym -> clean path has NO bias add (32 fewer v_add
// per wave-iter in the VALU-dominant loop).
__global__ __launch_bounds__(256, 4) void attn_fused(const bf16* __restrict__ Q,
                                                     const bf16* __restrict__ K,
                                                     const bf16* __restrict__ Vt,
                                                     const unsigned char* __restrict__ mask,
                                                     const float* __restrict__ gamma,
                                                     bf16* __restrict__ Out) {
  constexpr int S = 2048, E = 1024;
  constexpr float NEGB = -3.0e38f;                 // masked-key bias (exp2 -> 0)
  __shared__ alignas(16) bf16 Ks[2][64 * 64];
  __shared__ alignas(16) bf16 Vs[2][64 * 64];

  const int tid = threadIdx.x;
  const int wave = tid >> 6, lane = tid & 63;
  const int quad = lane >> 4, l15 = lane & 15;

  // XCD-grouping swizzle: hw XCD = (bx + 16*by)%8 = bx%8. For fixed work-bh,
  // blocks use bx in {bh&7, (bh&7)+8} -> constant bx%8 -> one XCD.
  const int bx = blockIdx.x, by = blockIdx.y;
  const int wx = (bx >> 3) | ((by & 7) << 1);      // q-tile index 0..15
  const int bh = (bx & 7) | (by & ~7);             // bh 0..63
  const int q0 = wx * 128;
  const int b = bh >> 4, h = bh & 15;

  const unsigned char* mg = mask + (size_t)b * S;

  // ---- per-wave "any key masked?" flag (2 loads + ballot; no LDS/barrier) ----
  bool anym;
  {
    const uint4* m4 = (const uint4*)mg;            // 64 lanes * 32B = 2048B = S
    uint4 x = m4[lane * 2], y = m4[lane * 2 + 1];
    unsigned o = (x.x | x.y | x.z | x.w) | (y.x | y.y | y.z | y.w);
    anym = __ballot(o != 0) != 0ull;
  }

  // staging lane offsets (8 chunks of 16B per 128B row, XOR swizzle by row&7)
  const int lrow = lane >> 3;                      // 0..7
  const int sx = ((lane & 7) ^ lrow) * 8;          // swizzled source chunk (elems)
  const size_t koff = (size_t)lrow * E + sx;       // K is [token][E]
  const size_t voff = (size_t)lrow * S + sx;       // Vt is [d][S]

  const bf16* Qg = Q + ((size_t)(b * S + q0)) * E + h * 64;
  const bf16* Kg = K + ((size_t)b * S) * E + h * 64;
  const bf16* Vg = Vt + ((size_t)bh * 64) * S;

  auto stageKV = [&](int bf_, int kt) {
#pragma unroll
    for (int p = 0; p < 2; ++p) {
      gll16(Kg + (size_t)(kt + wave * 16 + p * 8) * E + koff,
            &Ks[bf_][(wave * 16 + p * 8) * 64 + lane * 8]);
      gll16(Vg + (size_t)(wave * 16 + p * 8) * S + voff + kt,
            &Vs[bf_][(wave * 16 + p * 8) * 64 + lane * 8]);
    }
  };

  stageKV(0, 0);

  // ---- Q fragments: straight global->register (one-time 8MB total) ----
  bf16_8 qf[2][2];
#pragma unroll
  for (int mt = 0; mt < 2; ++mt)
#pragma unroll
    for (int ks = 0; ks < 2; ++ks)
      qf[mt][ks] = *(const bf16_8*)(Qg + (size_t)(wave * 32 + mt * 16 + l15) * E +
                                    ks * 32 + quad * 8);

  s16x8 onesP;
#pragma unroll
  for (int j = 0; j < 8; ++j) onesP[j] = (short)0x3F80;
  const bf16_8 onesA8 = __builtin_bit_cast(bf16_8, onesP);

  f32_4 accO[4][2] = {};   // [d-tile][q-tile], O^T C-layout
  f32_4 accR[2] = {};      // softmax denominators (ones^T . P^T), rows equal

  int buf = 0;
  for (int kt = 0; kt < S; kt += 64, buf ^= 1) {
    __syncthreads();                       // drains stage(cur) issued last iter
    if (kt + 64 < S) stageKV(buf ^ 1, kt + 64);

    // ---- S^T = K.Q^T : A = K-tile (LDS), B = Q (registers) ----
    f32_4 sT[4][2] = {};
    __builtin_amdgcn_s_setprio(1);
#pragma unroll
    for (int ks = 0; ks < 2; ++ks)
#pragma unroll
      for (int t = 0; t < 4; ++t) {
        bf16_8 af = *(const bf16_8*)&Ks[buf][(t * 16 + l15) * 64 +
                                            (((ks * 4 + quad) ^ (l15 & 7)) * 8)];
        sT[t][0] = MFMA_16x16x32(af, qf[0][ks], sT[t][0]);
        sT[t][1] = MFMA_16x16x32(af, qf[1][ks], sT[t][1]);
      }
    __builtin_amdgcn_s_setprio(0);

    // ---- softmax: scores already in exp2-space -> bare v_exp per score ----
    s16x4 pk[4][2];
    if (!anym) {
#pragma unroll
      for (int t = 0; t < 4; ++t)
#pragma unroll
        for (int mt = 0; mt < 2; ++mt) {
          float e0 = exp2fast(sT[t][mt][0]);
          float e1 = exp2fast(sT[t][mt][1]);
          float e2 = exp2fast(sT[t][mt][2]);
          float e3 = exp2fast(sT[t][mt][3]);
          uint2 u;
          u.x = bfbits(e0) | (bfbits(e1) << 16);
          u.y = bfbits(e2) | (bfbits(e3) << 16);
          pk[t][mt] = __builtin_bit_cast(s16x4, u);
        }
    } else {
#pragma unroll
      for (int t = 0; t < 4; ++t) {
        const unsigned um = *(const unsigned*)(mg + kt + t * 16 + quad * 4);
        const float bb0 = (um & 0xffu) ? NEGB : 0.0f;
        const float bb1 = (um & 0xff00u) ? NEGB : 0.0f;
        const float bb2 = (um & 0xff0000u) ? NEGB : 0.0f;
        const float bb3 = (um & 0xff000000u) ? NEGB : 0.0f;
#pragma unroll
        for (int mt = 0; mt < 2; ++mt) {
          float e0 = exp2fast(sT[t][mt][0] + bb0);
          float e1 = exp2fast(sT[t][mt][1] + bb1);
          float e2 = exp2fast(sT[t][mt][2] + bb2);
          float e3 = exp2fast(sT[t][mt][3] + bb3);
          uint2 u;
          u.x = bfbits(e0) | (bfbits(e1) << 16);
          u.y = bfbits(e2) | (bfbits(e3) << 16);
          pk[t][mt] = __builtin_bit_cast(s16x4, u);
        }
      }
    }

    // ---- O^T += V^T.P^T at full rate (x32): A = V^T b128 (LDS),
    //      B = {pk[2i],pk[2i+1]} register concat; denominator via ones-MFMA ----
    __builtin_amdgcn_s_setprio(1);
#pragma unroll
    for (int i2 = 0; i2 < 2; ++i2) {
      const bf16_8 pb0 = __builtin_bit_cast(bf16_8,
          __builtin_shufflevector(pk[2 * i2][0], pk[2 * i2 + 1][0], 0, 1, 2, 3, 4, 5, 6, 7));
      const bf16_8 pb1 = __builtin_bit_cast(bf16_8,
          __builtin_shufflevector(pk[2 * i2][1], pk[2 * i2 + 1][1], 0, 1, 2, 3, 4, 5, 6, 7));
      accR[0] = MFMA_16x16x32(onesA8, pb0, accR[0]);
      accR[1] = MFMA_16x16x32(onesA8, pb1, accR[1]);
      const int xo = ((i2 * 4 + quad) ^ (l15 & 7)) * 8;
#pragma unroll
      for (int dt = 0; dt < 4; ++dt) {
        bf16_8 vf = *(const bf16_8*)&Vs[buf][(dt * 16 + l15) * 64 + xo];
        accO[dt][0] = MFMA_16x16x32(vf, pb0, accO[dt][0]);
        accO[dt][1] = MFMA_16x16x32(vf, pb1, accO[dt][1]);
      }
    }
    __builtin_amdgcn_s_setprio(0);
  }

  // ---- finalize: accR holds full row-sum (K=32 spans all quads) ----
  const float g = gamma[h];
  float invv[2];
#pragma unroll
  for (int mt = 0; mt < 2; ++mt) invv[mt] = g / accR[mt][0];

  // accO C-layout: col=l15=query, row=quad*4+i = d within dt-tile
#pragma unroll
  for (int mt = 0; mt < 2; ++mt) {
    size_t token = (size_t)(b * S) + q0 + wave * 32 + mt * 16 + l15;
    bf16* orow = Out + token * E + h * 64;
#pragma unroll
    for (int dt = 0; dt < 4; ++dt) {
      bf16_4 ov;
      ov[0] = (bf16)(accO[dt][mt][0] * invv[mt]);
      ov[1] = (bf16)(accO[dt][mt][1] * invv[mt]);
      ov[2] = (bf16)(accO[dt][mt][2] * invv[mt]);
      ov[3] = (bf16)(accO[dt][mt][3] * invv[mt]);
      *(bf16_4*)(orow + dt * 16 + quad * 4) = ov;
    }
  }
}

// ---------------- launch ------------------------------------------------------
extern "C" void kernel_launch(void* const* d_in, const int* in_sizes, int n_in,
                              void* d_out, int out_size, void* d_ws, size_t ws_size,
                              hipStream_t stream) {
  constexpr int Bb = 4, S = 2048, E = 1024;
  constexpr int M = Bb * S;  // 8192

  const float* q = (const float*)d_in[0];
  const float* k = (const float*)d_in[1];
  const float* v = (const float*)d_in[2];
  const unsigned char* mask = (const unsigned char*)d_in[3];
  const float* Wq = (const float*)d_in[4];
  const float* Wk = (const float*)d_in[5];
  const float* Wv = (const float*)d_in[6];
  const float* Wo = (const float*)d_in[7];
  const float* gamma = (const float*)d_in[8];

  // ws (72 MiB): Wb[0,8M) | qb[8,24M) (later At) | kb[24,40M) | vb[40,56M) | Vt[56,72M)
  // d_out (32 MiB fp32, fully overwritten by final GEMM) doubles as Qp+Kp scratch.
  char* ws = (char*)d_ws;
  bf16* Wb = (bf16*)ws;
  bf16* qb = (bf16*)(ws + ((size_t)8 << 20));
  bf16* kb = (bf16*)(ws + ((size_t)24 << 20));
  bf16* vb = (bf16*)(ws + ((size_t)40 << 20));
  bf16* Vt = (bf16*)(ws + ((size_t)56 << 20));
  bf16* Qp = (bf16*)d_out;
  bf16* Kp = (bf16*)d_out + ((size_t)1 << 23);  // +16 MiB

  cvt_all<<<dim3(4096, 4), 256, 0, stream>>>(q, k, v, Wq, Wk, Wv, Wo, qb, kb, vb, Wb);

  gemm_qkv<<<dim3(M / 128, 24), 256, 0, stream>>>(qb, kb, vb, Wb, Qp, Kp, Vt);

  bf16* At = qb;  // qb dead after gemm_qkv
  attn_fused<<<dim3(S / 128, Bb * 16), 256, 0, stream>>>(Qp, Kp, Vt, mask, gamma, At);

  gemm_out<<<dim3(M / 128, E / 128), 256, 0, stream>>>(At, Wb + (3 << 20), (float*)d_out, M, E, E);
}

// Round 9
// 326.282 us; speedup vs baseline: 1.0363x; 1.0363x over previous
//
#include <hip/hip_runtime.h>
#include <hip/hip_bf16.h>
#include <cstdint>

typedef __bf16 bf16;
typedef __bf16 bf16_8 __attribute__((ext_vector_type(8)));
typedef __bf16 bf16_4 __attribute__((ext_vector_type(4)));
typedef float f32_4 __attribute__((ext_vector_type(4)));
typedef short s16x4 __attribute__((ext_vector_type(4)));
typedef short s16x8 __attribute__((ext_vector_type(8)));

#define MFMA_16x16x32(a, b, c) __builtin_amdgcn_mfma_f32_16x16x32_bf16((a), (b), (c), 0, 0, 0)

__device__ __forceinline__ void gll16(const void* g, void* l) {
  __builtin_amdgcn_global_load_lds((const __attribute__((address_space(1))) void*)g,
                                   (__attribute__((address_space(3))) void*)l, 16, 0, 0);
}

__device__ __forceinline__ float exp2fast(float x) {
#if __has_builtin(__builtin_amdgcn_exp2f)
  return __builtin_amdgcn_exp2f(x);
#else
  return __exp2f(x);
#endif
}

__device__ __forceinline__ unsigned bfbits(float x) {
  bf16 b = (bf16)x;
  return (unsigned)__builtin_bit_cast(unsigned short, b);
}

// ---------------- fused fp32 -> bf16 converter (activations + weights) -------
// y in [0,3): q/k/v activations, 8 elems/thread (4096 x-blocks).
// y == 3   : all four weight matrices concatenated, 4 elems/thread.
//            Wq (widx 0) is PRE-SCALED by (1/sqrt(64))*log2(e) so attention
//            scores arrive in exp2-space: softmax is a bare v_exp per score
//            (bf16 rounding is scale-invariant; fixed bias cancels in P/sum).
__global__ __launch_bounds__(256) void cvt_all(const float* __restrict__ q,
                                               const float* __restrict__ k,
                                               const float* __restrict__ v,
                                               const float* __restrict__ w0,
                                               const float* __restrict__ w1,
                                               const float* __restrict__ w2,
                                               const float* __restrict__ w3,
                                               bf16* __restrict__ qb,
                                               bf16* __restrict__ kb,
                                               bf16* __restrict__ vb,
                                               bf16* __restrict__ wb) {
  const int y = blockIdx.y;
  if (y < 3) {
    const float* src = y == 0 ? q : (y == 1 ? k : v);
    bf16* dst = y == 0 ? qb : (y == 1 ? kb : vb);
    size_t i = ((size_t)blockIdx.x * 256 + threadIdx.x) * 8;
    float4 f0 = *(const float4*)(src + i);
    float4 f1 = *(const float4*)(src + i + 4);
    bf16_8 o;
    o[0] = (bf16)f0.x; o[1] = (bf16)f0.y; o[2] = (bf16)f0.z; o[3] = (bf16)f0.w;
    o[4] = (bf16)f1.x; o[5] = (bf16)f1.y; o[6] = (bf16)f1.z; o[7] = (bf16)f1.w;
    *(bf16_8*)(dst + i) = o;
  } else {
    size_t i = ((size_t)blockIdx.x * 256 + threadIdx.x) * 4;
    const int widx = (int)(i >> 20);                 // block-uniform
    const size_t off = i & (((size_t)1 << 20) - 1);
    const float* srcs[4] = {w0, w1, w2, w3};
    const float sc = (widx == 0) ? 0.18033688f : 1.0f;  // 0.125*log2(e)
    float4 f = *(const float4*)(srcs[widx] + off);
    bf16_4 o;
    o[0] = (bf16)(f.x * sc); o[1] = (bf16)(f.y * sc);
    o[2] = (bf16)(f.z * sc); o[3] = (bf16)(f.w * sc);
    *(bf16_4*)(wb + i) = o;
  }
}

// ---------------- fused QKV projection GEMM ----------------------------------
// bf16 A via global_load_lds; T2 source-side slot swizzle (row&3) inverted at
// fragment read. REVERTED round-8's operand-swap epilogue: the bf16_4 stores
// at 2KB row stride hit 64 cachelines/instruction (vs 4 for the quad-coalesced
// scalar epilogue) and cost ~+15us across the two GEMMs.
// blockIdx.y in [0,24): tensor = y>>3 (0:q,1:k,2:v), n0 = (y&7)*128.
// Q/K written [token][E]; V written TRANSPOSED into Vt[(b*16+h)*64+d][s],
// with keys PAIR-PERMUTED within each 64-block:
//   k = t*16 + q*4 + j  ->  (t>>1)*32 + q*8 + (t&1)*4 + j
// so attn's PV step fetches x32 A-frags as single b128 LDS reads.
__global__ __launch_bounds__(256) void gemm_qkv(const bf16* __restrict__ Aq,
                                                const bf16* __restrict__ Ak,
                                                const bf16* __restrict__ Av,
                                                const bf16* __restrict__ W,
                                                bf16* __restrict__ Qp,
                                                bf16* __restrict__ Kp,
                                                bf16* __restrict__ Vt) {
  constexpr int BM = 128, BK = 32, K = 1024, N = 1024, M_S = 2048;
  __shared__ alignas(16) bf16 As[2][BM * BK];
  __shared__ alignas(16) bf16 Bs[2][BM * BK];

  const int tid = threadIdx.x;
  const int wave = tid >> 6, lane = tid & 63;
  const int quad = lane >> 4, l15 = lane & 15;
  const int wm = (wave & 1) * 64, wn = (wave >> 1) * 64;
  const int tensor = blockIdx.y >> 3;
  const int n0 = (blockIdx.y & 7) * 128;
  const size_t m0 = (size_t)blockIdx.x * BM;

  const bf16* A = tensor == 0 ? Aq : (tensor == 1 ? Ak : Av);
  const bf16* Bt = W + ((size_t)tensor << 20);

  f32_4 acc[4][4] = {};

  // swizzled source: lane covers row lane>>2, 16B slot (lane&3)^((lane>>2)&3)
  const size_t g_laneoff = (size_t)(lane >> 2) * K +
                           (size_t)(((lane & 3) ^ ((lane >> 2) & 3)) * 8);
  const bf16* Ag = A + (m0 + wave * 32) * (size_t)K + g_laneoff;
  const bf16* Bg = Bt + ((size_t)n0 + wave * 32) * (size_t)K + g_laneoff;
  const int l_off = wave * 32 * BK + lane * 8;

  auto stage = [&](int b, int k0) {
    gll16(Ag + k0, &As[b][l_off]);
    gll16(Ag + 16 * (size_t)K + k0, &As[b][l_off + 16 * BK]);
    gll16(Bg + k0, &Bs[b][l_off]);
    gll16(Bg + 16 * (size_t)K + k0, &Bs[b][l_off + 16 * BK]);
  };

  stage(0, 0);
  int buf = 0;
  for (int k0 = 0; k0 < K; k0 += BK, buf ^= 1) {
    __syncthreads();
    if (k0 + BK < K) stage(buf ^ 1, k0 + BK);

    const int slot = (quad ^ (l15 & 3)) * 8;   // inverse swizzle at read
    bf16_8 af[4], bfr[4];
#pragma unroll
    for (int mt = 0; mt < 4; ++mt)
      af[mt] = *(const bf16_8*)&As[buf][(wm + mt * 16 + l15) * BK + slot];
#pragma unroll
    for (int nt = 0; nt < 4; ++nt)
      bfr[nt] = *(const bf16_8*)&Bs[buf][(wn + nt * 16 + l15) * BK + slot];
#pragma unroll
    for (int mt = 0; mt < 4; ++mt)
#pragma unroll
      for (int nt = 0; nt < 4; ++nt)
        acc[mt][nt] = MFMA_16x16x32(af[mt], bfr[nt], acc[mt][nt]);
  }

  if (tensor < 2) {
    bf16* C = tensor == 0 ? Qp : Kp;
#pragma unroll
    for (int mt = 0; mt < 4; ++mt)
#pragma unroll
      for (int i = 0; i < 4; ++i) {
        size_t row = m0 + wm + mt * 16 + quad * 4 + i;
        bf16* cr = C + row * N + n0 + wn + l15;
#pragma unroll
        for (int nt = 0; nt < 4; ++nt) cr[nt * 16] = (bf16)acc[mt][nt][i];
      }
  } else {
    const int bb = (int)(m0 >> 11);
    const int sbase = (int)(m0 & 2047) + wm;
#pragma unroll
    for (int mt = 0; mt < 4; ++mt)
#pragma unroll
      for (int nt = 0; nt < 4; ++nt) {
        int col = n0 + wn + nt * 16 + l15;
        bf16_4 pk;
        pk[0] = (bf16)acc[mt][nt][0]; pk[1] = (bf16)acc[mt][nt][1];
        pk[2] = (bf16)acc[mt][nt][2]; pk[3] = (bf16)acc[mt][nt][3];
        // pair-permuted key index: mt*16+quad*4 -> (mt>>1)*32 + quad*8 + (mt&1)*4
        bf16* dst = Vt + ((size_t)(bb * 16 + (col >> 6)) * 64 + (col & 63)) * M_S +
                    sbase + (mt >> 1) * 32 + quad * 8 + (mt & 1) * 4;
        *(bf16_4*)dst = pk;
      }
  }
}

// ---------------- output projection GEMM (fp32 out) --------------------------
// Reverted to normal operand order + quad-coalesced scalar epilogue.
__global__ __launch_bounds__(256) void gemm_out(const bf16* __restrict__ A,
                                                const bf16* __restrict__ Bt,
                                                float* __restrict__ C,
                                                int M, int N, int K) {
  constexpr int BM = 128, BN = 128, BK = 32;
  __shared__ alignas(16) bf16 As[2][BM * BK];
  __shared__ alignas(16) bf16 Bs[2][BN * BK];

  const int tid = threadIdx.x;
  const int wave = tid >> 6, lane = tid & 63;
  const int quad = lane >> 4, l15 = lane & 15;
  const int wm = (wave & 1) * 64, wn = (wave >> 1) * 64;
  const size_t m0 = (size_t)blockIdx.x * BM;
  const size_t n0 = (size_t)blockIdx.y * BN;

  f32_4 acc[4][4] = {};

  const size_t g_laneoff = (size_t)(lane >> 2) * K +
                           (size_t)(((lane & 3) ^ ((lane >> 2) & 3)) * 8);
  const bf16* Ag = A + (m0 + wave * 32) * (size_t)K + g_laneoff;
  const bf16* Bg = Bt + (n0 + wave * 32) * (size_t)K + g_laneoff;
  const int l_off = wave * 32 * BK + lane * 8;

  auto stage = [&](int b, int k0) {
    gll16(Ag + k0, &As[b][l_off]);
    gll16(Ag + 16 * (size_t)K + k0, &As[b][l_off + 16 * BK]);
    gll16(Bg + k0, &Bs[b][l_off]);
    gll16(Bg + 16 * (size_t)K + k0, &Bs[b][l_off + 16 * BK]);
  };

  stage(0, 0);
  int buf = 0;
  for (int k0 = 0; k0 < K; k0 += BK, buf ^= 1) {
    __syncthreads();
    if (k0 + BK < K) stage(buf ^ 1, k0 + BK);

    const int slot = (quad ^ (l15 & 3)) * 8;
    bf16_8 af[4], bfr[4];
#pragma unroll
    for (int mt = 0; mt < 4; ++mt)
      af[mt] = *(const bf16_8*)&As[buf][(wm + mt * 16 + l15) * BK + slot];
#pragma unroll
    for (int nt = 0; nt < 4; ++nt)
      bfr[nt] = *(const bf16_8*)&Bs[buf][(wn + nt * 16 + l15) * BK + slot];
#pragma unroll
    for (int mt = 0; mt < 4; ++mt)
#pragma unroll
      for (int nt = 0; nt < 4; ++nt)
        acc[mt][nt] = MFMA_16x16x32(af[mt], bfr[nt], acc[mt][nt]);
  }

#pragma unroll
  for (int mt = 0; mt < 4; ++mt)
#pragma unroll
    for (int i = 0; i < 4; ++i) {
      size_t row = m0 + wm + mt * 16 + quad * 4 + i;
      float* cr = C + row * N + n0 + wn + l15;
#pragma unroll
      for (int nt = 0; nt < 4; ++nt) cr[nt * 16] = acc[mt][nt][i];
    }
}

// ---------------- fused flash attention, register-resident P -----------------
// 4 waves x 32 q-rows. K-tiles of 64, KV dbuf. (87.3 us measured in round 8.)
// S^T = K.Q^T (Q pre-scaled to exp2-space) -> softmax is a bare v_exp;
// exp(S^T) C-layout IS half a x32 B-frag; pair-permuted Vt makes each b128
// V read the matching x32 A-frag. Denominator via ones-MFMA.
// XCD-grouping swizzle; per-wave ballot anym; setprio around MFMA clusters;
// uniform branch on anym (clean path: bare v_exp, no bias add).
__global__ __launch_bounds__(256, 4) void attn_fused(const bf16* __restrict__ Q,
                                                     const bf16* __restrict__ K,
                                                     const bf16* __restrict__ Vt,
                                                     const unsigned char* __restrict__ mask,
                                                     const float* __restrict__ gamma,
                                                     bf16* __restrict__ Out) {
  constexpr int S = 2048, E = 1024;
  constexpr float NEGB = -3.0e38f;                 // masked-key bias (exp2 -> 0)
  __shared__ alignas(16) bf16 Ks[2][64 * 64];
  __shared__ alignas(16) bf16 Vs[2][64 * 64];

  const int tid = threadIdx.x;
  const int wave = tid >> 6, lane = tid & 63;
  const int quad = lane >> 4, l15 = lane & 15;

  // XCD-grouping swizzle: hw XCD = (bx + 16*by)%8 = bx%8. For fixed work-bh,
  // blocks use bx in {bh&7, (bh&7)+8} -> constant bx%8 -> one XCD.
  const int bx = blockIdx.x, by = blockIdx.y;
  const int wx = (bx >> 3) | ((by & 7) << 1);      // q-tile index 0..15
  const int bh = (bx & 7) | (by & ~7);             // bh 0..63
  const int q0 = wx * 128;
  const int b = bh >> 4, h = bh & 15;

  const unsigned char* mg = mask + (size_t)b * S;

  // ---- per-wave "any key masked?" flag (2 loads + ballot; no LDS/barrier) ----
  bool anym;
  {
    const uint4* m4 = (const uint4*)mg;            // 64 lanes * 32B = 2048B = S
    uint4 x = m4[lane * 2], y = m4[lane * 2 + 1];
    unsigned o = (x.x | x.y | x.z | x.w) | (y.x | y.y | y.z | y.w);
    anym = __ballot(o != 0) != 0ull;
  }

  // staging lane offsets (8 chunks of 16B per 128B row, XOR swizzle by row&7)
  const int lrow = lane >> 3;                      // 0..7
  const int sx = ((lane & 7) ^ lrow) * 8;          // swizzled source chunk (elems)
  const size_t koff = (size_t)lrow * E + sx;       // K is [token][E]
  const size_t voff = (size_t)lrow * S + sx;       // Vt is [d][S]

  const bf16* Qg = Q + ((size_t)(b * S + q0)) * E + h * 64;
  const bf16* Kg = K + ((size_t)b * S) * E + h * 64;
  const bf16* Vg = Vt + ((size_t)bh * 64) * S;

  auto stageKV = [&](int bf_, int kt) {
#pragma unroll
    for (int p = 0; p < 2; ++p) {
      gll16(Kg + (size_t)(kt + wave * 16 + p * 8) * E + koff,
            &Ks[bf_][(wave * 16 + p * 8) * 64 + lane * 8]);
      gll16(Vg + (size_t)(wave * 16 + p * 8) * S + voff + kt,
            &Vs[bf_][(wave * 16 + p * 8) * 64 + lane * 8]);
    }
  };

  stageKV(0, 0);

  // ---- Q fragments: straight global->register (one-time 8MB total) ----
  bf16_8 qf[2][2];
#pragma unroll
  for (int mt = 0; mt < 2; ++mt)
#pragma unroll
    for (int ks = 0; ks < 2; ++ks)
      qf[mt][ks] = *(const bf16_8*)(Qg + (size_t)(wave * 32 + mt * 16 + l15) * E +
                                    ks * 32 + quad * 8);

  s16x8 onesP;
#pragma unroll
  for (int j = 0; j < 8; ++j) onesP[j] = (short)0x3F80;
  const bf16_8 onesA8 = __builtin_bit_cast(bf16_8, onesP);

  f32_4 accO[4][2] = {};   // [d-tile][q-tile], O^T C-layout
  f32_4 accR[2] = {};      // softmax denominators (ones^T . P^T), rows equal

  int buf = 0;
  for (int kt = 0; kt < S; kt += 64, buf ^= 1) {
    __syncthreads();                       // drains stage(cur) issued last iter
    if (kt + 64 < S) stageKV(buf ^ 1, kt + 64);

    // ---- S^T = K.Q^T : A = K-tile (LDS), B = Q (registers) ----
    f32_4 sT[4][2] = {};
    __builtin_amdgcn_s_setprio(1);
#pragma unroll
    for (int ks = 0; ks < 2; ++ks)
#pragma unroll
      for (int t = 0; t < 4; ++t) {
        bf16_8 af = *(const bf16_8*)&Ks[buf][(t * 16 + l15) * 64 +
                                            (((ks * 4 + quad) ^ (l15 & 7)) * 8)];
        sT[t][0] = MFMA_16x16x32(af, qf[0][ks], sT[t][0]);
        sT[t][1] = MFMA_16x16x32(af, qf[1][ks], sT[t][1]);
      }
    __builtin_amdgcn_s_setprio(0);

    // ---- softmax: scores already in exp2-space -> bare v_exp per score ----
    s16x4 pk[4][2];
    if (!anym) {
#pragma unroll
      for (int t = 0; t < 4; ++t)
#pragma unroll
        for (int mt = 0; mt < 2; ++mt) {
          float e0 = exp2fast(sT[t][mt][0]);
          float e1 = exp2fast(sT[t][mt][1]);
          float e2 = exp2fast(sT[t][mt][2]);
          float e3 = exp2fast(sT[t][mt][3]);
          uint2 u;
          u.x = bfbits(e0) | (bfbits(e1) << 16);
          u.y = bfbits(e2) | (bfbits(e3) << 16);
          pk[t][mt] = __builtin_bit_cast(s16x4, u);
        }
    } else {
#pragma unroll
      for (int t = 0; t < 4; ++t) {
        const unsigned um = *(const unsigned*)(mg + kt + t * 16 + quad * 4);
        const float bb0 = (um & 0xffu) ? NEGB : 0.0f;
        const float bb1 = (um & 0xff00u) ? NEGB : 0.0f;
        const float bb2 = (um & 0xff0000u) ? NEGB : 0.0f;
        const float bb3 = (um & 0xff000000u) ? NEGB : 0.0f;
#pragma unroll
        for (int mt = 0; mt < 2; ++mt) {
          float e0 = exp2fast(sT[t][mt][0] + bb0);
          float e1 = exp2fast(sT[t][mt][1] + bb1);
          float e2 = exp2fast(sT[t][mt][2] + bb2);
          float e3 = exp2fast(sT[t][mt][3] + bb3);
          uint2 u;
          u.x = bfbits(e0) | (bfbits(e1) << 16);
          u.y = bfbits(e2) | (bfbits(e3) << 16);
          pk[t][mt] = __builtin_bit_cast(s16x4, u);
        }
      }
    }

    // ---- O^T += V^T.P^T at full rate (x32): A = V^T b128 (LDS),
    //      B = {pk[2i],pk[2i+1]} register concat; denominator via ones-MFMA ----
    __builtin_amdgcn_s_setprio(1);
#pragma unroll
    for (int i2 = 0; i2 < 2; ++i2) {
      const bf16_8 pb0 = __builtin_bit_cast(bf16_8,
          __builtin_shufflevector(pk[2 * i2][0], pk[2 * i2 + 1][0], 0, 1, 2, 3, 4, 5, 6, 7));
      const bf16_8 pb1 = __builtin_bit_cast(bf16_8,
          __builtin_shufflevector(pk[2 * i2][1], pk[2 * i2 + 1][1], 0, 1, 2, 3, 4, 5, 6, 7));
      accR[0] = MFMA_16x16x32(onesA8, pb0, accR[0]);
      accR[1] = MFMA_16x16x32(onesA8, pb1, accR[1]);
      const int xo = ((i2 * 4 + quad) ^ (l15 & 7)) * 8;
#pragma unroll
      for (int dt = 0; dt < 4; ++dt) {
        bf16_8 vf = *(const bf16_8*)&Vs[buf][(dt * 16 + l15) * 64 + xo];
        accO[dt][0] = MFMA_16x16x32(vf, pb0, accO[dt][0]);
        accO[dt][1] = MFMA_16x16x32(vf, pb1, accO[dt][1]);
      }
    }
    __builtin_amdgcn_s_setprio(0);
  }

  // ---- finalize: accR holds full row-sum (K=32 spans all quads) ----
  const float g = gamma[h];
  float invv[2];
#pragma unroll
  for (int mt = 0; mt < 2; ++mt) invv[mt] = g / accR[mt][0];

  // accO C-layout: col=l15=query, row=quad*4+i = d within dt-tile
#pragma unroll
  for (int mt = 0; mt < 2; ++mt) {
    size_t token = (size_t)(b * S) + q0 + wave * 32 + mt * 16 + l15;
    bf16* orow = Out + token * E + h * 64;
#pragma unroll
    for (int dt = 0; dt < 4; ++dt) {
      bf16_4 ov;
      ov[0] = (bf16)(accO[dt][mt][0] * invv[mt]);
      ov[1] = (bf16)(accO[dt][mt][1] * invv[mt]);
      ov[2] = (bf16)(accO[dt][mt][2] * invv[mt]);
      ov[3] = (bf16)(accO[dt][mt][3] * invv[mt]);
      *(bf16_4*)(orow + dt * 16 + quad * 4) = ov;
    }
  }
}

// ---------------- launch ------------------------------------------------------
extern "C" void kernel_launch(void* const* d_in, const int* in_sizes, int n_in,
                              void* d_out, int out_size, void* d_ws, size_t ws_size,
                              hipStream_t stream) {
  constexpr int Bb = 4, S = 2048, E = 1024;
  constexpr int M = Bb * S;  // 8192

  const float* q = (const float*)d_in[0];
  const float* k = (const float*)d_in[1];
  const float* v = (const float*)d_in[2];
  const unsigned char* mask = (const unsigned char*)d_in[3];
  const float* Wq = (const float*)d_in[4];
  const float* Wk = (const float*)d_in[5];
  const float* Wv = (const float*)d_in[6];
  const float* Wo = (const float*)d_in[7];
  const float* gamma = (const float*)d_in[8];

  // ws (72 MiB): Wb[0,8M) | qb[8,24M) (later At) | kb[24,40M) | vb[40,56M) | Vt[56,72M)
  // d_out (32 MiB fp32, fully overwritten by final GEMM) doubles as Qp+Kp scratch.
  char* ws = (char*)d_ws;
  bf16* Wb = (bf16*)ws;
  bf16* qb = (bf16*)(ws + ((size_t)8 << 20));
  bf16* kb = (bf16*)(ws + ((size_t)24 << 20));
  bf16* vb = (bf16*)(ws + ((size_t)40 << 20));
  bf16* Vt = (bf16*)(ws + ((size_t)56 << 20));
  bf16* Qp = (bf16*)d_out;
  bf16* Kp = (bf16*)d_out + ((size_t)1 << 23);  // +16 MiB

  cvt_all<<<dim3(4096, 4), 256, 0, stream>>>(q, k, v, Wq, Wk, Wv, Wo, qb, kb, vb, Wb);

  gemm_qkv<<<dim3(M / 128, 24), 256, 0, stream>>>(qb, kb, vb, Wb, Qp, Kp, Vt);

  bf16* At = qb;  // qb dead after gemm_qkv
  attn_fused<<<dim3(S / 128, Bb * 16), 256, 0, stream>>>(Qp, Kp, Vt, mask, gamma, At);

  gemm_out<<<dim3(M / 128, E / 128), 256, 0, stream>>>(At, Wb + (3 << 20), (float*)d_out, M, E, E);
}

// Round 10
// 325.381 us; speedup vs baseline: 1.0391x; 1.0028x over previous
//
#include <hip/hip_runtime.h>
#include <hip/hip_bf16.h>
#include <cstdint>

typedef __bf16 bf16;
typedef __bf16 bf16_8 __attribute__((ext_vector_type(8)));
typedef __bf16 bf16_4 __attribute__((ext_vector_type(4)));
typedef float f32_4 __attribute__((ext_vector_type(4)));
typedef short s16x4 __attribute__((ext_vector_type(4)));
typedef short s16x8 __attribute__((ext_vector_type(8)));

#define MFMA_16x16x32(a, b, c) __builtin_amdgcn_mfma_f32_16x16x32_bf16((a), (b), (c), 0, 0, 0)

__device__ __forceinline__ void gll16(const void* g, void* l) {
  __builtin_amdgcn_global_load_lds((const __attribute__((address_space(1))) void*)g,
                                   (__attribute__((address_space(3))) void*)l, 16, 0, 0);
}

__device__ __forceinline__ float exp2fast(float x) {
#if __has_builtin(__builtin_amdgcn_exp2f)
  return __builtin_amdgcn_exp2f(x);
#else
  return __exp2f(x);
#endif
}

__device__ __forceinline__ unsigned bfbits(float x) {
  bf16 b = (bf16)x;
  return (unsigned)__builtin_bit_cast(unsigned short, b);
}

// ---------------- fused fp32 -> bf16 converter (activations + weights) -------
// y in [0,3): q/k/v activations, 8 elems/thread (4096 x-blocks).
// y == 3   : all four weight matrices concatenated, 4 elems/thread.
//            Wq (widx 0) is PRE-SCALED by (1/sqrt(64))*log2(e) so attention
//            scores arrive in exp2-space: softmax is a bare v_exp per score
//            (bf16 rounding is scale-invariant; fixed bias cancels in P/sum).
__global__ __launch_bounds__(256) void cvt_all(const float* __restrict__ q,
                                               const float* __restrict__ k,
                                               const float* __restrict__ v,
                                               const float* __restrict__ w0,
                                               const float* __restrict__ w1,
                                               const float* __restrict__ w2,
                                               const float* __restrict__ w3,
                                               bf16* __restrict__ qb,
                                               bf16* __restrict__ kb,
                                               bf16* __restrict__ vb,
                                               bf16* __restrict__ wb) {
  const int y = blockIdx.y;
  if (y < 3) {
    const float* src = y == 0 ? q : (y == 1 ? k : v);
    bf16* dst = y == 0 ? qb : (y == 1 ? kb : vb);
    size_t i = ((size_t)blockIdx.x * 256 + threadIdx.x) * 8;
    float4 f0 = *(const float4*)(src + i);
    float4 f1 = *(const float4*)(src + i + 4);
    bf16_8 o;
    o[0] = (bf16)f0.x; o[1] = (bf16)f0.y; o[2] = (bf16)f0.z; o[3] = (bf16)f0.w;
    o[4] = (bf16)f1.x; o[5] = (bf16)f1.y; o[6] = (bf16)f1.z; o[7] = (bf16)f1.w;
    *(bf16_8*)(dst + i) = o;
  } else {
    size_t i = ((size_t)blockIdx.x * 256 + threadIdx.x) * 4;
    const int widx = (int)(i >> 20);                 // block-uniform
    const size_t off = i & (((size_t)1 << 20) - 1);
    const float* srcs[4] = {w0, w1, w2, w3};
    const float sc = (widx == 0) ? 0.18033688f : 1.0f;  // 0.125*log2(e)
    float4 f = *(const float4*)(srcs[widx] + off);
    bf16_4 o;
    o[0] = (bf16)(f.x * sc); o[1] = (bf16)(f.y * sc);
    o[2] = (bf16)(f.z * sc); o[3] = (bf16)(f.w * sc);
    *(bf16_4*)(wb + i) = o;
  }
}

// ---------------- fused QKV projection GEMM ----------------------------------
// NEW geometry: BM=256, BN=128, 8 waves (512 thr), waves = 4M x 2N; each wave
// still computes a 64x64 sub-tile with the SAME inner loop as the proven 128²
// kernel. MFMA per staged byte up 1.33x (128 MFMA / 24 gll16), barriers per
// output halved, LDS 48KB -> exactly 3 blocks/CU, grid 32x24=768 = 3/CU x 256.
// blockIdx.y in [0,24): tensor = y>>3 (0:q,1:k,2:v), n0 = (y&7)*128.
// Q/K written [token][E]; V written TRANSPOSED into Vt[(b*16+h)*64+d][s],
// with keys PAIR-PERMUTED within each 64-block:
//   k = t*16 + q*4 + j  ->  (t>>1)*32 + q*8 + (t&1)*4 + j
// so attn's PV step fetches x32 A-frags as single b128 LDS reads.
__global__ __launch_bounds__(512) void gemm_qkv(const bf16* __restrict__ Aq,
                                                const bf16* __restrict__ Ak,
                                                const bf16* __restrict__ Av,
                                                const bf16* __restrict__ W,
                                                bf16* __restrict__ Qp,
                                                bf16* __restrict__ Kp,
                                                bf16* __restrict__ Vt) {
  constexpr int BM = 256, BN = 128, BK = 32, K = 1024, N = 1024, M_S = 2048;
  __shared__ alignas(16) bf16 As[2][BM * BK];   // 2 x 16 KiB
  __shared__ alignas(16) bf16 Bs[2][BN * BK];   // 2 x 8 KiB

  const int tid = threadIdx.x;
  const int wave = tid >> 6, lane = tid & 63;
  const int quad = lane >> 4, l15 = lane & 15;
  const int wm = (wave & 3) * 64;                  // 4 M-slices
  const int wn = (wave >> 2) * 64;                 // 2 N-slices
  const int tensor = blockIdx.y >> 3;
  const int n0 = (blockIdx.y & 7) * 128;
  const size_t m0 = (size_t)blockIdx.x * BM;

  const bf16* A = tensor == 0 ? Aq : (tensor == 1 ? Ak : Av);
  const bf16* Bt = W + ((size_t)tensor << 20);

  f32_4 acc[4][4] = {};

  // swizzled source: lane covers row lane>>2, 16B slot (lane&3)^((lane>>2)&3)
  const size_t g_laneoff = (size_t)(lane >> 2) * K +
                           (size_t)(((lane & 3) ^ ((lane >> 2) & 3)) * 8);
  // A: each wave stages 32 rows (2 gll16); 8 waves cover 256 rows.
  const bf16* Ag = A + (m0 + wave * 32) * (size_t)K + g_laneoff;
  const int a_off = wave * 32 * BK + lane * 8;
  // B: each wave stages 16 rows (1 gll16); 8 waves cover 128 rows.
  const bf16* Bg = Bt + ((size_t)n0 + wave * 16) * (size_t)K + g_laneoff;
  const int b_off = wave * 16 * BK + lane * 8;

  auto stage = [&](int b, int k0) {
    gll16(Ag + k0, &As[b][a_off]);
    gll16(Ag + 16 * (size_t)K + k0, &As[b][a_off + 16 * BK]);
    gll16(Bg + k0, &Bs[b][b_off]);
  };

  stage(0, 0);
  int buf = 0;
  for (int k0 = 0; k0 < K; k0 += BK, buf ^= 1) {
    __syncthreads();
    if (k0 + BK < K) stage(buf ^ 1, k0 + BK);

    const int slot = (quad ^ (l15 & 3)) * 8;   // inverse swizzle at read
    bf16_8 af[4], bfr[4];
#pragma unroll
    for (int mt = 0; mt < 4; ++mt)
      af[mt] = *(const bf16_8*)&As[buf][(wm + mt * 16 + l15) * BK + slot];
#pragma unroll
    for (int nt = 0; nt < 4; ++nt)
      bfr[nt] = *(const bf16_8*)&Bs[buf][(wn + nt * 16 + l15) * BK + slot];
#pragma unroll
    for (int mt = 0; mt < 4; ++mt)
#pragma unroll
      for (int nt = 0; nt < 4; ++nt)
        acc[mt][nt] = MFMA_16x16x32(af[mt], bfr[nt], acc[mt][nt]);
  }

  if (tensor < 2) {
    bf16* C = tensor == 0 ? Qp : Kp;
#pragma unroll
    for (int mt = 0; mt < 4; ++mt)
#pragma unroll
      for (int i = 0; i < 4; ++i) {
        size_t row = m0 + wm + mt * 16 + quad * 4 + i;
        bf16* cr = C + row * N + n0 + wn + l15;
#pragma unroll
        for (int nt = 0; nt < 4; ++nt) cr[nt * 16] = (bf16)acc[mt][nt][i];
      }
  } else {
    const int bb = (int)(m0 >> 11);
    const int sbase = (int)(m0 & 2047) + wm;     // BM=256 divides 2048: no straddle
#pragma unroll
    for (int mt = 0; mt < 4; ++mt)
#pragma unroll
      for (int nt = 0; nt < 4; ++nt) {
        int col = n0 + wn + nt * 16 + l15;
        bf16_4 pk;
        pk[0] = (bf16)acc[mt][nt][0]; pk[1] = (bf16)acc[mt][nt][1];
        pk[2] = (bf16)acc[mt][nt][2]; pk[3] = (bf16)acc[mt][nt][3];
        // pair-permuted key index: mt*16+quad*4 -> (mt>>1)*32 + quad*8 + (mt&1)*4
        bf16* dst = Vt + ((size_t)(bb * 16 + (col >> 6)) * 64 + (col & 63)) * M_S +
                    sbase + (mt >> 1) * 32 + quad * 8 + (mt & 1) * 4;
        *(bf16_4*)dst = pk;
      }
  }
}

// ---------------- output projection GEMM (fp32 out) --------------------------
// Unchanged proven 128² structure (quad-coalesced scalar epilogue).
__global__ __launch_bounds__(256) void gemm_out(const bf16* __restrict__ A,
                                                const bf16* __restrict__ Bt,
                                                float* __restrict__ C,
                                                int M, int N, int K) {
  constexpr int BM = 128, BN = 128, BK = 32;
  __shared__ alignas(16) bf16 As[2][BM * BK];
  __shared__ alignas(16) bf16 Bs[2][BN * BK];

  const int tid = threadIdx.x;
  const int wave = tid >> 6, lane = tid & 63;
  const int quad = lane >> 4, l15 = lane & 15;
  const int wm = (wave & 1) * 64, wn = (wave >> 1) * 64;
  const size_t m0 = (size_t)blockIdx.x * BM;
  const size_t n0 = (size_t)blockIdx.y * BN;

  f32_4 acc[4][4] = {};

  const size_t g_laneoff = (size_t)(lane >> 2) * K +
                           (size_t)(((lane & 3) ^ ((lane >> 2) & 3)) * 8);
  const bf16* Ag = A + (m0 + wave * 32) * (size_t)K + g_laneoff;
  const bf16* Bg = Bt + (n0 + wave * 32) * (size_t)K + g_laneoff;
  const int l_off = wave * 32 * BK + lane * 8;

  auto stage = [&](int b, int k0) {
    gll16(Ag + k0, &As[b][l_off]);
    gll16(Ag + 16 * (size_t)K + k0, &As[b][l_off + 16 * BK]);
    gll16(Bg + k0, &Bs[b][l_off]);
    gll16(Bg + 16 * (size_t)K + k0, &Bs[b][l_off + 16 * BK]);
  };

  stage(0, 0);
  int buf = 0;
  for (int k0 = 0; k0 < K; k0 += BK, buf ^= 1) {
    __syncthreads();
    if (k0 + BK < K) stage(buf ^ 1, k0 + BK);

    const int slot = (quad ^ (l15 & 3)) * 8;
    bf16_8 af[4], bfr[4];
#pragma unroll
    for (int mt = 0; mt < 4; ++mt)
      af[mt] = *(const bf16_8*)&As[buf][(wm + mt * 16 + l15) * BK + slot];
#pragma unroll
    for (int nt = 0; nt < 4; ++nt)
      bfr[nt] = *(const bf16_8*)&Bs[buf][(wn + nt * 16 + l15) * BK + slot];
#pragma unroll
    for (int mt = 0; mt < 4; ++mt)
#pragma unroll
      for (int nt = 0; nt < 4; ++nt)
        acc[mt][nt] = MFMA_16x16x32(af[mt], bfr[nt], acc[mt][nt]);
  }

#pragma unroll
  for (int mt = 0; mt < 4; ++mt)
#pragma unroll
    for (int i = 0; i < 4; ++i) {
      size_t row = m0 + wm + mt * 16 + quad * 4 + i;
      float* cr = C + row * N + n0 + wn + l15;
#pragma unroll
      for (int nt = 0; nt < 4; ++nt) cr[nt * 16] = acc[mt][nt][i];
    }
}

// ---------------- fused flash attention, register-resident P -----------------
// 4 waves x 32 q-rows. K-tiles of 64, KV dbuf. (87.3-88.4 us measured.)
// S^T = K.Q^T (Q pre-scaled to exp2-space) -> softmax is a bare v_exp;
// exp(S^T) C-layout IS half a x32 B-frag; pair-permuted Vt makes each b128
// V read the matching x32 A-frag. Denominator via ones-MFMA.
// XCD-grouping swizzle; per-wave ballot anym; setprio around MFMA clusters;
// uniform branch on anym (clean path: bare v_exp, no bias add).
__global__ __launch_bounds__(256, 4) void attn_fused(const bf16* __restrict__ Q,
                                                     const bf16* __restrict__ K,
                                                     const bf16* __restrict__ Vt,
                                                     const unsigned char* __restrict__ mask,
                                                     const float* __restrict__ gamma,
                                                     bf16* __restrict__ Out) {
  constexpr int S = 2048, E = 1024;
  constexpr float NEGB = -3.0e38f;                 // masked-key bias (exp2 -> 0)
  __shared__ alignas(16) bf16 Ks[2][64 * 64];
  __shared__ alignas(16) bf16 Vs[2][64 * 64];

  const int tid = threadIdx.x;
  const int wave = tid >> 6, lane = tid & 63;
  const int quad = lane >> 4, l15 = lane & 15;

  // XCD-grouping swizzle: hw XCD = (bx + 16*by)%8 = bx%8. For fixed work-bh,
  // blocks use bx in {bh&7, (bh&7)+8} -> constant bx%8 -> one XCD.
  const int bx = blockIdx.x, by = blockIdx.y;
  const int wx = (bx >> 3) | ((by & 7) << 1);      // q-tile index 0..15
  const int bh = (bx & 7) | (by & ~7);             // bh 0..63
  const int q0 = wx * 128;
  const int b = bh >> 4, h = bh & 15;

  const unsigned char* mg = mask + (size_t)b * S;

  // ---- per-wave "any key masked?" flag (2 loads + ballot; no LDS/barrier) ----
  bool anym;
  {
    const uint4* m4 = (const uint4*)mg;            // 64 lanes * 32B = 2048B = S
    uint4 x = m4[lane * 2], y = m4[lane * 2 + 1];
    unsigned o = (x.x | x.y | x.z | x.w) | (y.x | y.y | y.z | y.w);
    anym = __ballot(o != 0) != 0ull;
  }

  // staging lane offsets (8 chunks of 16B per 128B row, XOR swizzle by row&7)
  const int lrow = lane >> 3;                      // 0..7
  const int sx = ((lane & 7) ^ lrow) * 8;          // swizzled source chunk (elems)
  const size_t koff = (size_t)lrow * E + sx;       // K is [token][E]
  const size_t voff = (size_t)lrow * S + sx;       // Vt is [d][S]

  const bf16* Qg = Q + ((size_t)(b * S + q0)) * E + h * 64;
  const bf16* Kg = K + ((size_t)b * S) * E + h * 64;
  const bf16* Vg = Vt + ((size_t)bh * 64) * S;

  auto stageKV = [&](int bf_, int kt) {
#pragma unroll
    for (int p = 0; p < 2; ++p) {
      gll16(Kg + (size_t)(kt + wave * 16 + p * 8) * E + koff,
            &Ks[bf_][(wave * 16 + p * 8) * 64 + lane * 8]);
      gll16(Vg + (size_t)(wave * 16 + p * 8) * S + voff + kt,
            &Vs[bf_][(wave * 16 + p * 8) * 64 + lane * 8]);
    }
  };

  stageKV(0, 0);

  // ---- Q fragments: straight global->register (one-time 8MB total) ----
  bf16_8 qf[2][2];
#pragma unroll
  for (int mt = 0; mt < 2; ++mt)
#pragma unroll
    for (int ks = 0; ks < 2; ++ks)
      qf[mt][ks] = *(const bf16_8*)(Qg + (size_t)(wave * 32 + mt * 16 + l15) * E +
                                    ks * 32 + quad * 8);

  s16x8 onesP;
#pragma unroll
  for (int j = 0; j < 8; ++j) onesP[j] = (short)0x3F80;
  const bf16_8 onesA8 = __builtin_bit_cast(bf16_8, onesP);

  f32_4 accO[4][2] = {};   // [d-tile][q-tile], O^T C-layout
  f32_4 accR[2] = {};      // softmax denominators (ones^T . P^T), rows equal

  int buf = 0;
  for (int kt = 0; kt < S; kt += 64, buf ^= 1) {
    __syncthreads();                       // drains stage(cur) issued last iter
    if (kt + 64 < S) stageKV(buf ^ 1, kt + 64);

    // ---- S^T = K.Q^T : A = K-tile (LDS), B = Q (registers) ----
    f32_4 sT[4][2] = {};
    __builtin_amdgcn_s_setprio(1);
#pragma unroll
    for (int ks = 0; ks < 2; ++ks)
#pragma unroll
      for (int t = 0; t < 4; ++t) {
        bf16_8 af = *(const bf16_8*)&Ks[buf][(t * 16 + l15) * 64 +
                                            (((ks * 4 + quad) ^ (l15 & 7)) * 8)];
        sT[t][0] = MFMA_16x16x32(af, qf[0][ks], sT[t][0]);
        sT[t][1] = MFMA_16x16x32(af, qf[1][ks], sT[t][1]);
      }
    __builtin_amdgcn_s_setprio(0);

    // ---- softmax: scores already in exp2-space -> bare v_exp per score ----
    s16x4 pk[4][2];
    if (!anym) {
#pragma unroll
      for (int t = 0; t < 4; ++t)
#pragma unroll
        for (int mt = 0; mt < 2; ++mt) {
          float e0 = exp2fast(sT[t][mt][0]);
          float e1 = exp2fast(sT[t][mt][1]);
          float e2 = exp2fast(sT[t][mt][2]);
          float e3 = exp2fast(sT[t][mt][3]);
          uint2 u;
          u.x = bfbits(e0) | (bfbits(e1) << 16);
          u.y = bfbits(e2) | (bfbits(e3) << 16);
          pk[t][mt] = __builtin_bit_cast(s16x4, u);
        }
    } else {
#pragma unroll
      for (int t = 0; t < 4; ++t) {
        const unsigned um = *(const unsigned*)(mg + kt + t * 16 + quad * 4);
        const float bb0 = (um & 0xffu) ? NEGB : 0.0f;
        const float bb1 = (um & 0xff00u) ? NEGB : 0.0f;
        const float bb2 = (um & 0xff0000u) ? NEGB : 0.0f;
        const float bb3 = (um & 0xff000000u) ? NEGB : 0.0f;
#pragma unroll
        for (int mt = 0; mt < 2; ++mt) {
          float e0 = exp2fast(sT[t][mt][0] + bb0);
          float e1 = exp2fast(sT[t][mt][1] + bb1);
          float e2 = exp2fast(sT[t][mt][2] + bb2);
          float e3 = exp2fast(sT[t][mt][3] + bb3);
          uint2 u;
          u.x = bfbits(e0) | (bfbits(e1) << 16);
          u.y = bfbits(e2) | (bfbits(e3) << 16);
          pk[t][mt] = __builtin_bit_cast(s16x4, u);
        }
      }
    }

    // ---- O^T += V^T.P^T at full rate (x32): A = V^T b128 (LDS),
    //      B = {pk[2i],pk[2i+1]} register concat; denominator via ones-MFMA ----
    __builtin_amdgcn_s_setprio(1);
#pragma unroll
    for (int i2 = 0; i2 < 2; ++i2) {
      const bf16_8 pb0 = __builtin_bit_cast(bf16_8,
          __builtin_shufflevector(pk[2 * i2][0], pk[2 * i2 + 1][0], 0, 1, 2, 3, 4, 5, 6, 7));
      const bf16_8 pb1 = __builtin_bit_cast(bf16_8,
          __builtin_shufflevector(pk[2 * i2][1], pk[2 * i2 + 1][1], 0, 1, 2, 3, 4, 5, 6, 7));
      accR[0] = MFMA_16x16x32(onesA8, pb0, accR[0]);
      accR[1] = MFMA_16x16x32(onesA8, pb1, accR[1]);
      const int xo = ((i2 * 4 + quad) ^ (l15 & 7)) * 8;
#pragma unroll
      for (int dt = 0; dt < 4; ++dt) {
        bf16_8 vf = *(const bf16_8*)&Vs[buf][(dt * 16 + l15) * 64 + xo];
        accO[dt][0] = MFMA_16x16x32(vf, pb0, accO[dt][0]);
        accO[dt][1] = MFMA_16x16x32(vf, pb1, accO[dt][1]);
      }
    }
    __builtin_amdgcn_s_setprio(0);
  }

  // ---- finalize: accR holds full row-sum (K=32 spans all quads) ----
  const float g = gamma[h];
  float invv[2];
#pragma unroll
  for (int mt = 0; mt < 2; ++mt) invv[mt] = g / accR[mt][0];

  // accO C-layout: col=l15=query, row=quad*4+i = d within dt-tile
#pragma unroll
  for (int mt = 0; mt < 2; ++mt) {
    size_t token = (size_t)(b * S) + q0 + wave * 32 + mt * 16 + l15;
    bf16* orow = Out + token * E + h * 64;
#pragma unroll
    for (int dt = 0; dt < 4; ++dt) {
      bf16_4 ov;
      ov[0] = (bf16)(accO[dt][mt][0] * invv[mt]);
      ov[1] = (bf16)(accO[dt][mt][1] * invv[mt]);
      ov[2] = (bf16)(accO[dt][mt][2] * invv[mt]);
      ov[3] = (bf16)(accO[dt][mt][3] * invv[mt]);
      *(bf16_4*)(orow + dt * 16 + quad * 4) = ov;
    }
  }
}

// ---------------- launch ------------------------------------------------------
extern "C" void kernel_launch(void* const* d_in, const int* in_sizes, int n_in,
                              void* d_out, int out_size, void* d_ws, size_t ws_size,
                              hipStream_t stream) {
  constexpr int Bb = 4, S = 2048, E = 1024;
  constexpr int M = Bb * S;  // 8192

  const float* q = (const float*)d_in[0];
  const float* k = (const float*)d_in[1];
  const float* v = (const float*)d_in[2];
  const unsigned char* mask = (const unsigned char*)d_in[3];
  const float* Wq = (const float*)d_in[4];
  const float* Wk = (const float*)d_in[5];
  const float* Wv = (const float*)d_in[6];
  const float* Wo = (const float*)d_in[7];
  const float* gamma = (const float*)d_in[8];

  // ws (72 MiB): Wb[0,8M) | qb[8,24M) (later At) | kb[24,40M) | vb[40,56M) | Vt[56,72M)
  // d_out (32 MiB fp32, fully overwritten by final GEMM) doubles as Qp+Kp scratch.
  char* ws = (char*)d_ws;
  bf16* Wb = (bf16*)ws;
  bf16* qb = (bf16*)(ws + ((size_t)8 << 20));
  bf16* kb = (bf16*)(ws + ((size_t)24 << 20));
  bf16* vb = (bf16*)(ws + ((size_t)40 << 20));
  bf16* Vt = (bf16*)(ws + ((size_t)56 << 20));
  bf16* Qp = (bf16*)d_out;
  bf16* Kp = (bf16*)d_out + ((size_t)1 << 23);  // +16 MiB

  cvt_all<<<dim3(4096, 4), 256, 0, stream>>>(q, k, v, Wq, Wk, Wv, Wo, qb, kb, vb, Wb);

  gemm_qkv<<<dim3(M / 256, 24), 512, 0, stream>>>(qb, kb, vb, Wb, Qp, Kp, Vt);

  bf16* At = qb;  // qb dead after gemm_qkv
  attn_fused<<<dim3(S / 128, Bb * 16), 256, 0, stream>>>(Qp, Kp, Vt, mask, gamma, At);

  gemm_out<<<dim3(M / 128, E / 128), 256, 0, stream>>>(At, Wb + (3 << 20), (float*)d_out, M, E, E);
}